// Round 1
// baseline (79.595 us; speedup 1.0000x reference)
//
#include <hip/hip_runtime.h>

// Geometric product over 3D PGA, 16-component multivectors.
// C[..., k] = sum_ij A[...,i] * B[...,j] * cayley[k,i,j]
// The Cayley table is fixed by the reference's basis; we rebuild it at
// COMPILE TIME with constexpr code mirroring the Python exactly, so the
// kernel never reads d_in[2] and the 256-term double loop constant-folds
// to the 192 nonzero +-1 FMAs.

namespace {

struct CayleyLUT {
    int idx[16][16];  // result component k for (i,j)
    int sgn[16][16];  // -1, 0, +1
};

constexpr CayleyLUT make_lut() {
    CayleyLUT L{};
    constexpr int MASK[16] = {0, 2, 4, 8, 1, 6, 10, 12, 3, 5, 9, 14, 7, 11, 13, 15};
    constexpr int SIGN[16] = {1, 1, 1, 1, 1, 1, 1, 1, -1, -1, -1, 1, 1, 1, 1, -1};
    for (int i = 0; i < 16; ++i) {
        for (int j = 0; j < 16; ++j) {
            L.idx[i][j] = 0;
            L.sgn[i][j] = 0;
            if (MASK[i] & MASK[j] & 1) continue;  // shared null e0 -> vanishes
            const int rm = MASK[i] ^ MASK[j];
            int k = 0;
            for (int t = 0; t < 16; ++t)
                if (MASK[t] == rm) k = t;
            int s = 1;
            for (int bit = 0; bit < 4; ++bit) {
                if ((MASK[i] >> bit) & 1) {
                    int lower = MASK[j] & ((1 << bit) - 1);
                    int c = 0;
                    for (int x = lower; x; x >>= 1) c += x & 1;
                    if (c & 1) s = -s;
                }
            }
            L.idx[i][j] = k;
            L.sgn[i][j] = SIGN[i] * SIGN[j] * s * SIGN[k];
        }
    }
    return L;
}

constexpr CayleyLUT LUT = make_lut();

constexpr int MV_PER_BLOCK = 256;  // one MV per thread per tile
constexpr int PAD = 20;            // floats per MV row in LDS (16B-aligned, bank-friendly)

__global__ __launch_bounds__(256) void gp_kernel(const float* __restrict__ A,
                                                 const float* __restrict__ B,
                                                 float* __restrict__ C,
                                                 long long n_mv) {
    __shared__ float sA[MV_PER_BLOCK * PAD];  // 20 KiB
    __shared__ float sB[MV_PER_BLOCK * PAD];  // 20 KiB
    const int t = threadIdx.x;
    const long long base_mv = (long long)blockIdx.x * MV_PER_BLOCK;
    const long long rem = n_mv - base_mv;
    const int mv_here = rem < MV_PER_BLOCK ? (int)rem : MV_PER_BLOCK;
    const int nf4 = mv_here * 4;  // float4s in this tile per operand

    const float4* __restrict__ A4 = reinterpret_cast<const float4*>(A) + base_mv * 4;
    const float4* __restrict__ B4 = reinterpret_cast<const float4*>(B) + base_mv * 4;
    float4* __restrict__ C4 = reinterpret_cast<float4*>(C) + base_mv * 4;

    // Stage in: fully coalesced float4 loads, padded scatter into LDS.
#pragma unroll
    for (int r = 0; r < 4; ++r) {
        const int f = t + 256 * r;
        if (f < nf4) {
            const float4 va = A4[f];
            const float4 vb = B4[f];
            const int o = (f >> 2) * PAD + (f & 3) * 4;
            *reinterpret_cast<float4*>(&sA[o]) = va;
            *reinterpret_cast<float4*>(&sB[o]) = vb;
        }
    }
    __syncthreads();

    if (t < mv_here) {
        float a[16], b[16];
#pragma unroll
        for (int q = 0; q < 4; ++q) {
            const float4 va = *reinterpret_cast<const float4*>(&sA[t * PAD + 4 * q]);
            const float4 vb = *reinterpret_cast<const float4*>(&sB[t * PAD + 4 * q]);
            a[4 * q + 0] = va.x; a[4 * q + 1] = va.y; a[4 * q + 2] = va.z; a[4 * q + 3] = va.w;
            b[4 * q + 0] = vb.x; b[4 * q + 1] = vb.y; b[4 * q + 2] = vb.z; b[4 * q + 3] = vb.w;
        }
        float c[16];
#pragma unroll
        for (int k = 0; k < 16; ++k) c[k] = 0.0f;
        // Fully unrolled; LUT is constexpr -> folds to 192 v_fma_f32.
#pragma unroll
        for (int i = 0; i < 16; ++i) {
#pragma unroll
            for (int j = 0; j < 16; ++j) {
                const int s = LUT.sgn[i][j];
                if (s != 0) {
                    const int k = LUT.idx[i][j];
                    c[k] = fmaf(s > 0 ? a[i] : -a[i], b[j], c[k]);
                }
            }
        }
        // Stage out into sA: row t is only touched by thread t after barrier 1,
        // so reusing the buffer is race-free.
#pragma unroll
        for (int q = 0; q < 4; ++q) {
            float4 v;
            v.x = c[4 * q + 0]; v.y = c[4 * q + 1]; v.z = c[4 * q + 2]; v.w = c[4 * q + 3];
            *reinterpret_cast<float4*>(&sA[t * PAD + 4 * q]) = v;
        }
    }
    __syncthreads();

    // Stage out: padded gather from LDS, fully coalesced float4 stores.
#pragma unroll
    for (int r = 0; r < 4; ++r) {
        const int f = t + 256 * r;
        if (f < nf4) {
            const int o = (f >> 2) * PAD + (f & 3) * 4;
            C4[f] = *reinterpret_cast<const float4*>(&sA[o]);
        }
    }
}

}  // namespace

extern "C" void kernel_launch(void* const* d_in, const int* in_sizes, int n_in,
                              void* d_out, int out_size, void* d_ws, size_t ws_size,
                              hipStream_t stream) {
    const float* A = (const float*)d_in[0];
    const float* B = (const float*)d_in[1];
    float* C = (float*)d_out;
    const long long n_mv = (long long)in_sizes[0] / 16;
    const int nblocks = (int)((n_mv + MV_PER_BLOCK - 1) / MV_PER_BLOCK);
    gp_kernel<<<nblocks, 256, 0, stream>>>(A, B, C, n_mv);
}